// Round 14
// baseline (349.353 us; speedup 1.0000x reference)
//
#include <hip/hip_runtime.h>
#include <math.h>

#define D_    64
#define K_    1024
#define N_    131072
#define HW_   4096
#define TAU   4e-5f
#define NST   32            // k-steps; each step = one 16-code tile per K-half

typedef unsigned long long ull;
typedef unsigned short ushort;
typedef short  bf16x8  __attribute__((ext_vector_type(8)));
typedef float  f32x4   __attribute__((ext_vector_type(4)));
typedef ushort ushort8 __attribute__((ext_vector_type(8)));

__device__ __forceinline__ ushort f2bf(float f) {        // RNE float->bf16
    unsigned u = __float_as_uint(f);
    return (ushort)((u + 0x7FFFu + ((u >> 16) & 1u)) >> 16);
}
__device__ __forceinline__ float b2f(ushort h) {
    return __uint_as_float((unsigned)h << 16);
}
// bank-conflict-free slot: seg*16 + (code^seg); write: 8 segs -> 8 bank-quads
#define SLOT(seg, code) ((seg) * 16 + ((code) ^ (seg)))

// ---- prep (K-only): eh/el/e2/embT, zero hist/cnt/ssqd ----
__global__ __launch_bounds__(256)
void vq_prep(const float* __restrict__ emb, ushort* __restrict__ ehg,
             ushort* __restrict__ elg, float* __restrict__ e2g,
             float* __restrict__ embT, int* __restrict__ hist,
             int* __restrict__ cnt, double* __restrict__ ssqd) {
    const int n = blockIdx.x * 256 + threadIdx.x;
    if (n < K_) {
        const float* er = emb + (size_t)n * D_;
        float e2 = 0.0f;
        #pragma unroll
        for (int d8 = 0; d8 < 8; ++d8) {
            ushort8 hh, ll;
            #pragma unroll
            for (int j = 0; j < 8; ++j) {
                float e = er[d8 * 8 + j];
                e2 = fmaf(e, e, e2);                     // ascending d
                ushort h = f2bf(e);
                hh[j] = h;
                ll[j] = f2bf(e - b2f(h));
                embT[(size_t)(d8 * 8 + j) * K_ + n] = e; // [d][k] for exact kernel
            }
            *(ushort8*)(ehg + (size_t)n * D_ + d8 * 8) = hh;
            *(ushort8*)(elg + (size_t)n * D_ + d8 * 8) = ll;
        }
        e2g[n] = e2;
        hist[n] = 0;
    }
    if (n == 0 && blockIdx.x == 0) { *cnt = 0; *ssqd = 0.0; }
}

// ---- phase 1: bf16x3 MFMA top-2; 128 rows/block, K split across wave pairs,
//      LDS B-staging (swizzled, double-buffered), fused apply ----
__global__ __launch_bounds__(256, 4)
void vq_mfma(const float* __restrict__ x, const float* __restrict__ emb,
             const ushort* __restrict__ ehg, const ushort* __restrict__ elg,
             const float* __restrict__ e2g, float* __restrict__ zq_out,
             int* __restrict__ list, int* __restrict__ cnt,
             int* __restrict__ hist, double* __restrict__ ssqd) {
    __shared__ ushort bst[2][2][2][128][8];  // [buf][kh][half][slot][8] = 16 KB
    __shared__ float lv1[4][64], lv2[4][64];
    __shared__ int   lk1[4][64];
    __shared__ int   lkfin[128];

    const int tid = threadIdx.x;
    const int wv  = tid >> 6;          // (rg, kh)
    const int rg  = wv >> 1;
    const int kh  = wv & 1;
    const int l   = tid & 63;
    const int g   = l >> 4;
    const int c16 = l & 15;
    const int n0b = blockIdx.x * 128;
    const int n0w = n0b + rg * 64;

    // staging roles: 512 ushort8/step, 2 per thread
    const int r0i   = tid;             // role 0
    const int r1i   = tid + 256;       // role 1
    const int kh0   = r0i >> 8,        kh1   = r1i >> 8;
    const int half0 = (r0i >> 7) & 1,  half1 = (r1i >> 7) & 1;
    const int code0 = (r0i >> 3) & 15, code1 = (r1i >> 3) & 15;
    const int seg0  = r0i & 7,         seg1  = r1i & 7;
    const ushort* s0Base = (half0 ? elg : ehg) + (size_t)(kh0 * NST * 16 + code0) * D_ + seg0 * 8;
    const ushort* s1Base = (half1 ? elg : ehg) + (size_t)(kh1 * NST * 16 + code1) * D_ + seg1 * 8;
    ushort* s0Dst[2] = { &bst[0][kh0][half0][SLOT(seg0, code0)][0],
                         &bst[1][kh0][half0][SLOT(seg0, code0)][0] };
    ushort* s1Dst[2] = { &bst[0][kh1][half1][SLOT(seg1, code1)][0],
                         &bst[1][kh1][half1][SLOT(seg1, code1)][0] };

    // ---- A fragments (64 rows per row-group; both kh waves load same rows, L1-hot)
    bf16x8 ah[4][2], al[4][2];
    #pragma unroll
    for (int t = 0; t < 4; ++t) {
        const int row = n0w + t * 16 + c16;
        const int b = row >> 12, hw = row & (HW_ - 1);
        const float* xr = x + (size_t)b * (D_ * HW_) + hw;
        #pragma unroll
        for (int s = 0; s < 2; ++s) {
            #pragma unroll
            for (int j = 0; j < 8; ++j) {
                float z = xr[(size_t)(g * 8 + s * 32 + j) * HW_];
                ushort h = f2bf(z);
                ah[t][s][j] = (short)h;
                al[t][s][j] = (short)f2bf(z - b2f(h));
            }
        }
    }

    float v1[16], v2[16]; int k1[16];
    #pragma unroll
    for (int st = 0; st < 16; ++st) { v1[st] = 3.4e38f; v2[st] = 3.4e38f; k1[st] = 0; }

    // ---- prologue: stage step 0 into buf 0 ----
    *(ushort8*)(s0Dst[0]) = *(const ushort8*)(s0Base);
    *(ushort8*)(s1Dst[0]) = *(const ushort8*)(s1Base);
    __syncthreads();

    for (int s = 0; s < NST; ++s) {
        const int cur = s & 1;
        const bool more = (s + 1) < NST;
        ushort8 pf0, pf1;
        if (more) {
            pf0 = *(const ushort8*)(s0Base + (size_t)(s + 1) * 16 * D_);
            pf1 = *(const ushort8*)(s1Base + (size_t)(s + 1) * 16 * D_);
        }

        const bf16x8 bh0 = *(const bf16x8*)(&bst[cur][kh][0][SLOT(g,     c16)][0]);
        const bf16x8 bh1 = *(const bf16x8*)(&bst[cur][kh][0][SLOT(g + 4, c16)][0]);
        const bf16x8 bl0 = *(const bf16x8*)(&bst[cur][kh][1][SLOT(g,     c16)][0]);
        const bf16x8 bl1 = *(const bf16x8*)(&bst[cur][kh][1][SLOT(g + 4, c16)][0]);
        const int   c_  = (kh * NST + s) * 16 + c16;
        const float E2  = e2g[c_];

        f32x4 ac[4];
        #pragma unroll
        for (int t = 0; t < 4; ++t) {
            f32x4 a = {0.0f, 0.0f, 0.0f, 0.0f};
            a = __builtin_amdgcn_mfma_f32_16x16x32_bf16(ah[t][0], bh0, a, 0, 0, 0);
            a = __builtin_amdgcn_mfma_f32_16x16x32_bf16(al[t][0], bh0, a, 0, 0, 0);
            a = __builtin_amdgcn_mfma_f32_16x16x32_bf16(ah[t][1], bh1, a, 0, 0, 0);
            a = __builtin_amdgcn_mfma_f32_16x16x32_bf16(al[t][1], bh1, a, 0, 0, 0);
            a = __builtin_amdgcn_mfma_f32_16x16x32_bf16(ah[t][0], bl0, a, 0, 0, 0);
            a = __builtin_amdgcn_mfma_f32_16x16x32_bf16(ah[t][1], bl1, a, 0, 0, 0);
            ac[t] = a;
        }
        // dist' = e2 - 2*dot (r2 row-constant: cancels in argmin AND margin)
        #pragma unroll
        for (int t = 0; t < 4; ++t) {
            #pragma unroll
            for (int q = 0; q < 4; ++q) {
                float dist = fmaf(-2.0f, ac[t][q], E2);
                const int st = t * 4 + q;
                float vmax = fmaxf(dist, v1[st]);
                bool lt = dist < v1[st];
                k1[st] = lt ? c_ : k1[st];
                v1[st] = fminf(dist, v1[st]);
                v2[st] = fminf(v2[st], vmax);
            }
        }

        if (more) {
            *(ushort8*)(s0Dst[cur ^ 1]) = pf0;
            *(ushort8*)(s1Dst[cur ^ 1]) = pf1;
        }
        __syncthreads();
    }

    // ---- merge top-2 across the 16 lanes of each lane-group ----
    #pragma unroll
    for (int off = 1; off < 16; off <<= 1) {
        #pragma unroll
        for (int st = 0; st < 16; ++st) {
            float w1 = __shfl_xor(v1[st], off, 64);
            float w2 = __shfl_xor(v2[st], off, 64);
            int   wk = __shfl_xor(k1[st], off, 64);
            float lose = (w1 < v1[st]) ? v1[st] : w1;
            v2[st] = fminf(fminf(v2[st], w2), lose);
            if (w1 < v1[st]) { v1[st] = w1; k1[st] = wk; }
        }
    }

    if (c16 == 0) {
        #pragma unroll
        for (int t = 0; t < 4; ++t) {
            #pragma unroll
            for (int q = 0; q < 4; ++q) {
                const int st = t * 4 + q;
                const int rr = t * 16 + 4 * g + q;       // row within 64-group
                lv1[wv][rr] = v1[st];
                lv2[wv][rr] = v2[st];
                lk1[wv][rr] = k1[st];
            }
        }
    }
    __syncthreads();

    // ---- merge the two K-halves per row; flag near-ties ----
    if (tid < 128) {
        const int rgm = tid >> 6, rr = tid & 63;
        const float a1 = lv1[rgm * 2 + 0][rr], b1 = lv1[rgm * 2 + 1][rr];
        const float a2 = lv2[rgm * 2 + 0][rr], b2 = lv2[rgm * 2 + 1][rr];
        float v1m; int k1m;
        if (b1 < a1) { v1m = b1; k1m = lk1[rgm * 2 + 1][rr]; }
        else         { v1m = a1; k1m = lk1[rgm * 2 + 0][rr]; }
        const float v2m = fminf(fmaxf(a1, b1), fminf(a2, b2));
        int kk;
        if (!(v2m - v1m > TAU)) {                        // near-tie -> exact fallback
            int i = atomicAdd(cnt, 1);
            list[i] = n0b + tid;
            kk = -1;
        } else {
            kk = k1m;
            atomicAdd(&hist[kk], 1);
        }
        lkfin[tid] = kk;
    }
    __syncthreads();

    // ---- fused apply for confident rows (x re-read is L1/L2-hot) ----
    const int lr = tid & 127;          // block-local row
    const int dh = tid >> 7;           // d half
    const int n  = n0b + lr;
    const int b2_ = n >> 12, hw2 = n & (HW_ - 1);
    const float* xr2  = x      + (size_t)b2_ * (D_ * HW_) + hw2;
    float*       outr = zq_out + (size_t)b2_ * (D_ * HW_) + hw2;
    const int kk = lkfin[lr];
    float ls = 0.0f;
    if (kk >= 0) {
        const float* er = emb + (size_t)kk * D_ + dh * 32;
        #pragma unroll
        for (int dd = 0; dd < 32; ++dd) {
            const int d = dh * 32 + dd;
            float zv = xr2[(size_t)d * HW_];
            float t  = er[dd] - zv;
            ls = fmaf(t, t, ls);
            outr[(size_t)d * HW_] = zv + t;
        }
    }
    #pragma unroll
    for (int o = 32; o > 0; o >>= 1) ls += __shfl_down(ls, o, 64);
    if (l == 0) atomicAdd(ssqd, (double)ls);
}

// ---- exact fallback: bitwise-proven chain over all K + fused apply ----
__global__ __launch_bounds__(256)
void vq_exact(const float* __restrict__ x, const float* __restrict__ emb,
              const float* __restrict__ embT, const float* __restrict__ e2g,
              const int* __restrict__ list, const int* __restrict__ cnt,
              float* __restrict__ zq_out, int* __restrict__ hist,
              double* __restrict__ ssqd) {
    const int l  = threadIdx.x & 63;
    const int gw = (blockIdx.x * 256 + threadIdx.x) >> 6;
    const int nw = (gridDim.x * 256) >> 6;
    const int C  = *cnt;
    for (int i = gw; i < C; i += nw) {
        const int n = list[i];
        const int b = n >> 12, hw = n & (HW_ - 1);
        const float* xr = x + (size_t)b * (D_ * HW_) + hw;
        const float zval = xr[(size_t)l * HW_];
        float r2 = 0.0f;
        float s[16];
        #pragma unroll
        for (int j = 0; j < 16; ++j) s[j] = 0.0f;
        for (int d = 0; d < D_; ++d) {
            const float zd = __shfl(zval, d, 64);
            r2 = fmaf(zd, zd, r2);                        // ascending-d chain
            const float* erow = embT + (size_t)d * K_ + l * 4;   // lane l: codes 256p+4l+c
            const float4 e0 = *(const float4*)(erow);
            const float4 e1 = *(const float4*)(erow + 256);
            const float4 e2 = *(const float4*)(erow + 512);
            const float4 e3 = *(const float4*)(erow + 768);
            s[0]  = fmaf(zd, e0.x, s[0]);  s[1]  = fmaf(zd, e0.y, s[1]);   // ascending-d
            s[2]  = fmaf(zd, e0.z, s[2]);  s[3]  = fmaf(zd, e0.w, s[3]);   // single chains
            s[4]  = fmaf(zd, e1.x, s[4]);  s[5]  = fmaf(zd, e1.y, s[5]);
            s[6]  = fmaf(zd, e1.z, s[6]);  s[7]  = fmaf(zd, e1.w, s[7]);
            s[8]  = fmaf(zd, e2.x, s[8]);  s[9]  = fmaf(zd, e2.y, s[9]);
            s[10] = fmaf(zd, e2.z, s[10]); s[11] = fmaf(zd, e2.w, s[11]);
            s[12] = fmaf(zd, e3.x, s[12]); s[13] = fmaf(zd, e3.y, s[13]);
            s[14] = fmaf(zd, e3.z, s[14]); s[15] = fmaf(zd, e3.w, s[15]);
        }
        ull best = ~0ull;
        #pragma unroll
        for (int j = 0; j < 16; ++j) {
            const int k = (j >> 2) * 256 + l * 4 + (j & 3);
            float dist = fmaf(-2.0f, s[j], r2 + e2g[k]);  // bitwise == proven chain
            ull p = ((ull)__float_as_uint(dist) << 32) | (unsigned)k;
            if (p < best) best = p;
        }
        #pragma unroll
        for (int off = 1; off < 64; off <<= 1) {
            ull q = __shfl_xor(best, off, 64);
            if (q < best) best = q;
        }
        const int k = (int)(best & 0xffffffffull);
        const float e = emb[(size_t)k * D_ + l];          // lane l holds z_d, d=l
        const float t = e - zval;
        float ps = t * t;
        float* outr = zq_out + (size_t)b * (D_ * HW_) + hw;
        outr[(size_t)l * HW_] = zval + t;
        #pragma unroll
        for (int off = 32; off > 0; off >>= 1) ps += __shfl_down(ps, off, 64);
        if (l == 0) {
            atomicAdd(&hist[k], 1);
            atomicAdd(ssqd, (double)ps);
        }
    }
}

__global__ __launch_bounds__(1024)
void vq_final(const int* __restrict__ hist, const double* __restrict__ ssqd,
              float* __restrict__ out_loss, float* __restrict__ out_perp) {
    __shared__ float wred[16];
    int t = threadIdx.x;
    float cnt = (float)hist[t];
    float em  = cnt / (float)N_;
    float s   = em * logf(em + 1e-10f);
    #pragma unroll
    for (int o = 32; o > 0; o >>= 1) s += __shfl_down(s, o, 64);
    if ((t & 63) == 0) wred[t >> 6] = s;
    __syncthreads();
    if (t == 0) {
        float tot = 0.0f;
        for (int w = 0; w < 16; ++w) tot += wred[w];
        *out_perp = expf(-tot);
        float mse = (float)(*ssqd / (double)((size_t)N_ * D_));
        *out_loss = mse + 0.25f * mse;
    }
}

extern "C" void kernel_launch(void* const* d_in, const int* in_sizes, int n_in,
                              void* d_out, int out_size, void* d_ws, size_t ws_size,
                              hipStream_t stream) {
    const float* x   = (const float*)d_in[0];
    const float* emb = (const float*)d_in[1];
    float* out  = (float*)d_out;
    float* loss = out;
    float* zq   = out + 1;
    float* perp = out + 1 + (size_t)N_ * D_;

    char* w = (char*)d_ws;
    int*    list = (int*)w;     w += (size_t)N_ * 4;
    ushort* ehg  = (ushort*)w;  w += (size_t)K_ * D_ * 2;
    ushort* elg  = (ushort*)w;  w += (size_t)K_ * D_ * 2;
    float*  embT = (float*)w;   w += (size_t)K_ * D_ * 4;
    float*  e2g  = (float*)w;   w += (size_t)K_ * 4;
    int*    hist = (int*)w;     w += (size_t)K_ * 4;
    int*    cnt  = (int*)w;     w += 16;
    double* ssqd = (double*)w;

    vq_prep<<<dim3(4), dim3(256), 0, stream>>>(emb, ehg, elg, e2g, embT, hist, cnt, ssqd);
    vq_mfma<<<dim3(N_ / 128), dim3(256), 0, stream>>>(x, emb, ehg, elg, e2g, zq, list, cnt, hist, ssqd);
    vq_exact<<<dim3(2048), dim3(256), 0, stream>>>(x, emb, embT, e2g, list, cnt, zq, hist, ssqd);
    vq_final<<<dim3(1), dim3(1024), 0, stream>>>(hist, ssqd, loss, perp);
}

// Round 15
// 148.214 us; speedup vs baseline: 2.3571x; 2.3571x over previous
//
#include <hip/hip_runtime.h>
#include <math.h>

#define D_    64
#define K_    1024
#define N_    131072
#define HW_   4096
#define TAU   4e-5f
#define NKT   64            // k-tiles of 16 codes

typedef unsigned long long ull;
typedef unsigned short ushort;
typedef short  bf16x8  __attribute__((ext_vector_type(8)));
typedef float  f32x4   __attribute__((ext_vector_type(4)));
typedef ushort ushort8 __attribute__((ext_vector_type(8)));

__device__ __forceinline__ ushort f2bf(float f) {        // RNE float->bf16
    unsigned u = __float_as_uint(f);
    return (ushort)((u + 0x7FFFu + ((u >> 16) & 1u)) >> 16);
}
__device__ __forceinline__ float b2f(ushort h) {
    return __uint_as_float((unsigned)h << 16);
}
// bank-conflict-free slot (round-14-proven: conflicts -> 0):
// write side: 8 segs -> 8 distinct bank-quads; read side: per 8 lanes all 8 quads
#define SLOT(seg, code) ((seg) * 16 + ((code) ^ (seg)))

// LDS-only barrier: drain ds ops, but leave global prefetch loads IN FLIGHT
// (hipcc's __syncthreads would drain vmcnt(0) -> kills the pipeline)
__device__ __forceinline__ void block_sync_lds() {
    asm volatile("s_waitcnt lgkmcnt(0)" ::: "memory");
    __builtin_amdgcn_s_barrier();
}

// ---- prep (K-only): eh/el/e2/embT, zero hist/cnt/ssqd ----
__global__ __launch_bounds__(256)
void vq_prep(const float* __restrict__ emb, ushort* __restrict__ ehg,
             ushort* __restrict__ elg, float* __restrict__ e2g,
             float* __restrict__ embT, int* __restrict__ hist,
             int* __restrict__ cnt, double* __restrict__ ssqd) {
    const int n = blockIdx.x * 256 + threadIdx.x;
    if (n < K_) {
        const float* er = emb + (size_t)n * D_;
        float e2 = 0.0f;
        #pragma unroll
        for (int d8 = 0; d8 < 8; ++d8) {
            ushort8 hh, ll;
            #pragma unroll
            for (int j = 0; j < 8; ++j) {
                float e = er[d8 * 8 + j];
                e2 = fmaf(e, e, e2);                     // ascending d
                ushort h = f2bf(e);
                hh[j] = h;
                ll[j] = f2bf(e - b2f(h));
                embT[(size_t)(d8 * 8 + j) * K_ + n] = e; // [d][k] for exact kernel
            }
            *(ushort8*)(ehg + (size_t)n * D_ + d8 * 8) = hh;
            *(ushort8*)(elg + (size_t)n * D_ + d8 * 8) = ll;
        }
        e2g[n] = e2;
        hist[n] = 0;
    }
    if (n == 0 && blockIdx.x == 0) { *cnt = 0; *ssqd = 0.0; }
}

// One k-tile: compute from bst[CUR]; ds_write prefetched tile S+1; issue load S+3.
#define STEP(CUR, S, PF)                                                      \
    {                                                                         \
        const bf16x8 bh0 = *(const bf16x8*)(&bst[CUR][0][SLOT(g,     c16)][0]); \
        const bf16x8 bh1 = *(const bf16x8*)(&bst[CUR][0][SLOT(g + 4, c16)][0]); \
        const bf16x8 bl0 = *(const bf16x8*)(&bst[CUR][1][SLOT(g,     c16)][0]); \
        const bf16x8 bl1 = *(const bf16x8*)(&bst[CUR][1][SLOT(g + 4, c16)][0]); \
        const int   c_  = (S) * 16 + c16;                                     \
        const float E2  = e2g[c_];                                            \
        f32x4 ac[4];                                                          \
        _Pragma("unroll")                                                     \
        for (int t = 0; t < 4; ++t) {                                         \
            f32x4 a = {0.0f, 0.0f, 0.0f, 0.0f};                               \
            a = __builtin_amdgcn_mfma_f32_16x16x32_bf16(ah[t][0], bh0, a, 0, 0, 0); \
            a = __builtin_amdgcn_mfma_f32_16x16x32_bf16(al[t][0], bh0, a, 0, 0, 0); \
            a = __builtin_amdgcn_mfma_f32_16x16x32_bf16(ah[t][1], bh1, a, 0, 0, 0); \
            a = __builtin_amdgcn_mfma_f32_16x16x32_bf16(al[t][1], bh1, a, 0, 0, 0); \
            a = __builtin_amdgcn_mfma_f32_16x16x32_bf16(ah[t][0], bl0, a, 0, 0, 0); \
            a = __builtin_amdgcn_mfma_f32_16x16x32_bf16(ah[t][1], bl1, a, 0, 0, 0); \
            ac[t] = a;                                                        \
        }                                                                     \
        /* dist' = e2 - 2*dot (r2 row-constant: cancels in argmin AND margin) */ \
        _Pragma("unroll")                                                     \
        for (int t = 0; t < 4; ++t) {                                         \
            _Pragma("unroll")                                                 \
            for (int q = 0; q < 4; ++q) {                                     \
                float dist = fmaf(-2.0f, ac[t][q], E2);                       \
                const int st = t * 4 + q;                                     \
                float vmax = fmaxf(dist, v1[st]);                             \
                bool lt = dist < v1[st];                                      \
                k1[st] = lt ? c_ : k1[st];                                    \
                v1[st] = fminf(dist, v1[st]);                                 \
                v2[st] = fminf(v2[st], vmax);                                 \
            }                                                                 \
        }                                                                     \
        if ((S) + 1 < NKT)                                                    \
            *(ushort8*)(&bst[(CUR) ^ 1][sHalf][sSlot][0]) = PF;               \
        if ((S) + 3 < NKT)                                                    \
            PF = *(const ushort8*)(sBase + (size_t)((S) + 3) * 16 * D_);      \
        block_sync_lds();                                                     \
    }

// ---- phase 1: bf16x3 MFMA top-2; 256 rows/block, full K/wave,
//      swizzled LDS B-staging, depth-2 prefetch, raw LDS barrier ----
__global__ __launch_bounds__(256, 2)
void vq_mfma(const float* __restrict__ x, const float* __restrict__ emb,
             const ushort* __restrict__ ehg, const ushort* __restrict__ elg,
             const float* __restrict__ e2g, float* __restrict__ zq_out,
             int* __restrict__ list, int* __restrict__ cnt,
             int* __restrict__ hist, double* __restrict__ ssqd) {
    __shared__ ushort bst[2][2][128][8];   // [buf][half][slot][8] = 8 KB
    __shared__ int lkfin[256];

    const int tid = threadIdx.x;
    const int wv  = tid >> 6;
    const int l   = tid & 63;
    const int g   = l >> 4;
    const int c16 = l & 15;
    const int n0b = blockIdx.x * 256;
    const int n0w = n0b + wv * 64;

    // staging role: one ushort8 per thread per tile
    const int sHalf = tid >> 7;        // 0 = h, 1 = l
    const int sS    = tid & 127;
    const int sCode = sS >> 3;         // 0..15
    const int sSeg  = sS & 7;          // 0..7
    const int sSlot = SLOT(sSeg, sCode);
    const ushort* sBase = (sHalf ? elg : ehg) + (size_t)sCode * D_ + sSeg * 8;

    // ---- A fragments (64 rows/wave). A and B share the slot->k bijection. ----
    bf16x8 ah[4][2], al[4][2];
    #pragma unroll
    for (int t = 0; t < 4; ++t) {
        const int row = n0w + t * 16 + c16;
        const int b = row >> 12, hw = row & (HW_ - 1);
        const float* xr = x + (size_t)b * (D_ * HW_) + hw;
        #pragma unroll
        for (int s = 0; s < 2; ++s) {
            #pragma unroll
            for (int j = 0; j < 8; ++j) {
                float z = xr[(size_t)(g * 8 + s * 32 + j) * HW_];
                ushort h = f2bf(z);
                ah[t][s][j] = (short)h;
                al[t][s][j] = (short)f2bf(z - b2f(h));
            }
        }
    }

    float v1[16], v2[16]; int k1[16];
    #pragma unroll
    for (int st = 0; st < 16; ++st) { v1[st] = 3.4e38f; v2[st] = 3.4e38f; k1[st] = 0; }

    // ---- prologue: stage tile 0; prefetch tiles 1,2 into registers ----
    *(ushort8*)(&bst[0][sHalf][sSlot][0]) = *(const ushort8*)(sBase);
    ushort8 pf0 = *(const ushort8*)(sBase + (size_t)1 * 16 * D_);
    ushort8 pf1 = *(const ushort8*)(sBase + (size_t)2 * 16 * D_);
    __syncthreads();

    #pragma unroll 1
    for (int s = 0; s < NKT; s += 2) {
        STEP(0, s,     pf0)
        STEP(1, s + 1, pf1)
    }

    // ---- merge top-2 across the 16 lanes of each lane-group ----
    #pragma unroll
    for (int off = 1; off < 16; off <<= 1) {
        #pragma unroll
        for (int st = 0; st < 16; ++st) {
            float w1 = __shfl_xor(v1[st], off, 64);
            float w2 = __shfl_xor(v2[st], off, 64);
            int   wk = __shfl_xor(k1[st], off, 64);
            float lose = (w1 < v1[st]) ? v1[st] : w1;
            v2[st] = fminf(fminf(v2[st], w2), lose);
            if (w1 < v1[st]) { v1[st] = w1; k1[st] = wk; }
        }
    }

    if (c16 == 0) {
        #pragma unroll
        for (int t = 0; t < 4; ++t) {
            #pragma unroll
            for (int q = 0; q < 4; ++q) {
                const int st = t * 4 + q;
                const int rr = wv * 64 + t * 16 + 4 * g + q;   // block-local row
                int kk;
                if (!(v2[st] - v1[st] > TAU)) {                // near-tie -> exact
                    int i = atomicAdd(cnt, 1);
                    list[i] = n0b + rr;
                    kk = -1;
                } else {
                    kk = k1[st];
                    atomicAdd(&hist[kk], 1);
                }
                lkfin[rr] = kk;
            }
        }
    }
    __syncthreads();

    // ---- fused apply for confident rows (x re-read is L1/L2-hot) ----
    const int n  = n0b + tid;
    const int b2_ = n >> 12, hw2 = n & (HW_ - 1);
    const float* xr2  = x      + (size_t)b2_ * (D_ * HW_) + hw2;
    float*       outr = zq_out + (size_t)b2_ * (D_ * HW_) + hw2;
    const int kk = lkfin[tid];
    float ls = 0.0f;
    if (kk >= 0) {
        const float* er = emb + (size_t)kk * D_;
        #pragma unroll
        for (int d = 0; d < D_; ++d) {
            float zv = xr2[(size_t)d * HW_];
            float t  = er[d] - zv;
            ls = fmaf(t, t, ls);
            outr[(size_t)d * HW_] = zv + t;
        }
    }
    #pragma unroll
    for (int o = 32; o > 0; o >>= 1) ls += __shfl_down(ls, o, 64);
    if (l == 0) atomicAdd(ssqd, (double)ls);
}

// ---- exact fallback: bitwise-proven chain over all K + fused apply ----
__global__ __launch_bounds__(256)
void vq_exact(const float* __restrict__ x, const float* __restrict__ emb,
              const float* __restrict__ embT, const float* __restrict__ e2g,
              const int* __restrict__ list, const int* __restrict__ cnt,
              float* __restrict__ zq_out, int* __restrict__ hist,
              double* __restrict__ ssqd) {
    const int l  = threadIdx.x & 63;
    const int gw = (blockIdx.x * 256 + threadIdx.x) >> 6;
    const int nw = (gridDim.x * 256) >> 6;
    const int C  = *cnt;
    for (int i = gw; i < C; i += nw) {
        const int n = list[i];
        const int b = n >> 12, hw = n & (HW_ - 1);
        const float* xr = x + (size_t)b * (D_ * HW_) + hw;
        const float zval = xr[(size_t)l * HW_];
        float r2 = 0.0f;
        float s[16];
        #pragma unroll
        for (int j = 0; j < 16; ++j) s[j] = 0.0f;
        for (int d = 0; d < D_; ++d) {
            const float zd = __shfl(zval, d, 64);
            r2 = fmaf(zd, zd, r2);                        // ascending-d chain
            const float* erow = embT + (size_t)d * K_ + l * 4;   // lane l: codes 256p+4l+c
            const float4 e0 = *(const float4*)(erow);
            const float4 e1 = *(const float4*)(erow + 256);
            const float4 e2 = *(const float4*)(erow + 512);
            const float4 e3 = *(const float4*)(erow + 768);
            s[0]  = fmaf(zd, e0.x, s[0]);  s[1]  = fmaf(zd, e0.y, s[1]);   // ascending-d
            s[2]  = fmaf(zd, e0.z, s[2]);  s[3]  = fmaf(zd, e0.w, s[3]);   // single chains
            s[4]  = fmaf(zd, e1.x, s[4]);  s[5]  = fmaf(zd, e1.y, s[5]);
            s[6]  = fmaf(zd, e1.z, s[6]);  s[7]  = fmaf(zd, e1.w, s[7]);
            s[8]  = fmaf(zd, e2.x, s[8]);  s[9]  = fmaf(zd, e2.y, s[9]);
            s[10] = fmaf(zd, e2.z, s[10]); s[11] = fmaf(zd, e2.w, s[11]);
            s[12] = fmaf(zd, e3.x, s[12]); s[13] = fmaf(zd, e3.y, s[13]);
            s[14] = fmaf(zd, e3.z, s[14]); s[15] = fmaf(zd, e3.w, s[15]);
        }
        ull best = ~0ull;
        #pragma unroll
        for (int j = 0; j < 16; ++j) {
            const int k = (j >> 2) * 256 + l * 4 + (j & 3);
            float dist = fmaf(-2.0f, s[j], r2 + e2g[k]);  // bitwise == proven chain
            ull p = ((ull)__float_as_uint(dist) << 32) | (unsigned)k;
            if (p < best) best = p;
        }
        #pragma unroll
        for (int off = 1; off < 64; off <<= 1) {
            ull q = __shfl_xor(best, off, 64);
            if (q < best) best = q;
        }
        const int k = (int)(best & 0xffffffffull);
        const float e = emb[(size_t)k * D_ + l];          // lane l holds z_d, d=l
        const float t = e - zval;
        float ps = t * t;
        float* outr = zq_out + (size_t)b * (D_ * HW_) + hw;
        outr[(size_t)l * HW_] = zval + t;
        #pragma unroll
        for (int off = 32; off > 0; off >>= 1) ps += __shfl_down(ps, off, 64);
        if (l == 0) {
            atomicAdd(&hist[k], 1);
            atomicAdd(ssqd, (double)ps);
        }
    }
}

__global__ __launch_bounds__(1024)
void vq_final(const int* __restrict__ hist, const double* __restrict__ ssqd,
              float* __restrict__ out_loss, float* __restrict__ out_perp) {
    __shared__ float wred[16];
    int t = threadIdx.x;
    float cnt = (float)hist[t];
    float em  = cnt / (float)N_;
    float s   = em * logf(em + 1e-10f);
    #pragma unroll
    for (int o = 32; o > 0; o >>= 1) s += __shfl_down(s, o, 64);
    if ((t & 63) == 0) wred[t >> 6] = s;
    __syncthreads();
    if (t == 0) {
        float tot = 0.0f;
        for (int w = 0; w < 16; ++w) tot += wred[w];
        *out_perp = expf(-tot);
        float mse = (float)(*ssqd / (double)((size_t)N_ * D_));
        *out_loss = mse + 0.25f * mse;
    }
}

extern "C" void kernel_launch(void* const* d_in, const int* in_sizes, int n_in,
                              void* d_out, int out_size, void* d_ws, size_t ws_size,
                              hipStream_t stream) {
    const float* x   = (const float*)d_in[0];
    const float* emb = (const float*)d_in[1];
    float* out  = (float*)d_out;
    float* loss = out;
    float* zq   = out + 1;
    float* perp = out + 1 + (size_t)N_ * D_;

    char* w = (char*)d_ws;
    int*    list = (int*)w;     w += (size_t)N_ * 4;
    ushort* ehg  = (ushort*)w;  w += (size_t)K_ * D_ * 2;
    ushort* elg  = (ushort*)w;  w += (size_t)K_ * D_ * 2;
    float*  embT = (float*)w;   w += (size_t)K_ * D_ * 4;
    float*  e2g  = (float*)w;   w += (size_t)K_ * 4;
    int*    hist = (int*)w;     w += (size_t)K_ * 4;
    int*    cnt  = (int*)w;     w += 16;
    double* ssqd = (double*)w;

    vq_prep<<<dim3(4), dim3(256), 0, stream>>>(emb, ehg, elg, e2g, embT, hist, cnt, ssqd);
    vq_mfma<<<dim3(N_ / 256), dim3(256), 0, stream>>>(x, emb, ehg, elg, e2g, zq, list, cnt, hist, ssqd);
    vq_exact<<<dim3(2048), dim3(256), 0, stream>>>(x, emb, embT, e2g, list, cnt, zq, hist, ssqd);
    vq_final<<<dim3(1), dim3(1024), 0, stream>>>(hist, ssqd, loss, perp);
}